// Round 1
// baseline (1212.111 us; speedup 1.0000x reference)
//
#include <hip/hip_runtime.h>

// entmax-1.5 attention, fp32 baseline.
// B=4 H=8 S=1024 D=128. Grid: 32 (b*h) * 128 (q-tiles of 8) = 4096 blocks, 256 thr.
// Block layout: qi = t>>5 (8 local queries), g = t&31 (32 lanes per query).
// Scores for the 8x1024 tile live in LDS; each thread also holds its own 32
// scores in registers for the bisection (tau solve) phase.

#define S_    1024
#define D_    128
#define TQ    8
#define TK    32
#define NB    4096
#define NEG_INF_F (-1.0e12f)
#define NITER 26

__global__ __launch_bounds__(256, 2)
void entmax_attn(const float* __restrict__ Q, const float* __restrict__ K,
                 const float* __restrict__ V, const int* __restrict__ M,
                 float* __restrict__ O)
{
    __shared__ float sc[TQ][S_ + 4];      // +4 pad: 2-way (free) bank pattern
    __shared__ float kv_s[TK][D_ + 4];    // K/V staging tile, 16B-aligned rows
    __shared__ float q_s[TQ][D_ + 4];

    const int t  = threadIdx.x;
    const int qi = t >> 5;        // local query 0..7
    const int g  = t & 31;        // lane within query group
    const int bh = blockIdx.x >> 7;
    const int qt = blockIdx.x & 127;
    const int b  = bh >> 3;

    const float* qbase = Q + ((size_t)bh * S_ + (size_t)qt * TQ) * D_;
    const float* kbase = K + (size_t)bh * S_ * D_;
    const float* vbase = V + (size_t)bh * S_ * D_;
    const int*   mbase = M + ((size_t)b * S_ + (size_t)qt * TQ) * S_;
    float*       obase = O + ((size_t)bh * S_ + (size_t)qt * TQ) * D_;

    // stage Q tile: 8 rows x 128 floats = 256 float4, one per thread
    {
        const int r = t >> 5, c = t & 31;
        const float4 val = ((const float4*)qbase)[r * (D_ / 4) + c];
        *(float4*)&q_s[r][c * 4] = val;
    }
    // first __syncthreads() below covers q_s visibility

    const float scale = 0.08838834764831845f;  // 1/sqrt(128)
    float mx = -3.0e38f;

    // ---- phase 1: scores = QK^T * scale, masked; also track row max --------
    #pragma unroll 1
    for (int kt = 0; kt < S_ / TK; ++kt) {
        __syncthreads();
        const float4* src = (const float4*)(kbase + (size_t)kt * TK * D_);
        #pragma unroll
        for (int u = 0; u < 4; ++u) {           // 32x128 = 1024 float4 staged
            const int i = t + u * 256;
            const int r = i >> 5, c = i & 31;
            *(float4*)&kv_s[r][c * 4] = src[r * (D_ / 4) + c];
        }
        __syncthreads();

        float acc = 0.f;
        #pragma unroll
        for (int d = 0; d < D_; d += 4) {
            const float4 qv = *(const float4*)&q_s[qi][d];
            const float4 kv = *(const float4*)&kv_s[g][d];
            acc = fmaf(qv.x, kv.x, acc);
            acc = fmaf(qv.y, kv.y, acc);
            acc = fmaf(qv.z, kv.z, acc);
            acc = fmaf(qv.w, kv.w, acc);
        }
        const int kg = kt * TK + g;
        float s = acc * scale;
        if (mbase[(size_t)qi * S_ + kg] == 0) s = NEG_INF_F;
        sc[qi][kg] = s;                 // thread (qi,g) owns keys {32*kt + g}
        mx = fmaxf(mx, s);
    }

    // row max over the 32 lanes of this query group (contiguous half-wave)
    #pragma unroll
    for (int off = 16; off > 0; off >>= 1)
        mx = fmaxf(mx, __shfl_xor(mx, off, 64));

    // pull own 32 scores into registers, normalized: x = (s - max)/2  (<= 0)
    float x[32];
    #pragma unroll
    for (int j = 0; j < 32; ++j)
        x[j] = (sc[qi][g + 32 * j] - mx) * 0.5f;

    // ---- phase 2: bisection for tau in [-1,0]: f(tau)=sum max(0,x-tau)^2 = 1
    // f(-1) >= 1 (max element alone gives 1), f(0) <= ... <= f is monotone dec.
    float lo = -1.f, hi = 0.f;
    #pragma unroll 1
    for (int it = 0; it < NITER; ++it) {
        const float tau = 0.5f * (lo + hi);
        float sum = 0.f;
        #pragma unroll
        for (int j = 0; j < 32; ++j) {
            float dd = x[j] - tau;
            dd = fmaxf(dd, 0.f);
            sum = fmaf(dd, dd, sum);
        }
        #pragma unroll
        for (int off = 16; off > 0; off >>= 1)
            sum += __shfl_xor(sum, off, 64);
        const bool ge = (sum >= 1.f);
        lo = ge ? tau : lo;             // branchless: group-uniform anyway
        hi = ge ? hi : tau;
    }
    const float tau = 0.5f * (lo + hi);

    // y = max(0, x - tau)^2, write back to LDS for the PV phase
    #pragma unroll
    for (int j = 0; j < 32; ++j) {
        const float dd = fmaxf(x[j] - tau, 0.f);
        sc[qi][g + 32 * j] = dd * dd;
    }

    // ---- phase 3: O = y @ V; thread (qi,g) owns out[qi][4g..4g+3] ----------
    float o0 = 0.f, o1 = 0.f, o2 = 0.f, o3 = 0.f;
    #pragma unroll 1
    for (int vt = 0; vt < S_ / TK; ++vt) {
        __syncthreads();                 // guards kv_s reuse + sc y-visibility
        const float4* src = (const float4*)(vbase + (size_t)vt * TK * D_);
        #pragma unroll
        for (int u = 0; u < 4; ++u) {
            const int i = t + u * 256;
            const int r = i >> 5, c = i & 31;
            *(float4*)&kv_s[r][c * 4] = src[r * (D_ / 4) + c];
        }
        __syncthreads();
        #pragma unroll
        for (int kk = 0; kk < TK; ++kk) {
            const float yv = sc[qi][vt * TK + kk];               // broadcast
            const float4 vv = *(const float4*)&kv_s[kk][g * 4];
            o0 = fmaf(yv, vv.x, o0);
            o1 = fmaf(yv, vv.y, o1);
            o2 = fmaf(yv, vv.z, o2);
            o3 = fmaf(yv, vv.w, o3);
        }
    }
    const float4 ov = {o0, o1, o2, o3};
    *(float4*)&obase[(size_t)qi * D_ + g * 4] = ov;   // coalesced: 2 full rows/wave
}

extern "C" void kernel_launch(void* const* d_in, const int* in_sizes, int n_in,
                              void* d_out, int out_size, void* d_ws, size_t ws_size,
                              hipStream_t stream) {
    const float* q = (const float*)d_in[0];
    const float* k = (const float*)d_in[1];
    const float* v = (const float*)d_in[2];
    const int*   m = (const int*)d_in[3];
    float*       o = (float*)d_out;
    entmax_attn<<<dim3(NB), dim3(256), 0, stream>>>(q, k, v, m, o);
}

// Round 4
// 299.619 us; speedup vs baseline: 4.0455x; 4.0455x over previous
//
#include <hip/hip_runtime.h>

// entmax-1.5 attention, diagnostic-simplified MFMA version.
// B=4 H=8 S=1024 D=128. 2048 blocks (32 bh x 64 q-tiles of 16), 256 thr (4 waves).
// Phase 1: QK^T via mfma_16x16x32_bf16, raw scaled scores dumped to a full
//          16x1024 LDS buffer using the C/D map (col=lane&15, row=quad*4+reg).
// Phase 2: each thread re-gathers 64 scores of ONE row by direct [row][key]
//          indexing, applies mask+max+bisection (round-1-proven solver) in
//          registers, writes y back to the same buffer (becomes P).
// Phase 3: O = P @ V via MFMA, A-fragments read contiguously from P buffer.

#define S_ 1024
#define D_ 128
#define NEG_INF_F (-1.0e12f)
#define SCALE_F 0.08838834764831845f  // 1/sqrt(128)
#define NITER 26

typedef float f32x4 __attribute__((ext_vector_type(4)));
typedef short short8 __attribute__((ext_vector_type(8)));

__device__ __forceinline__ ushort f2bf(float x) {   // RNE f32 -> bf16
    unsigned u = __builtin_bit_cast(unsigned, x);
    u += 0x7FFFu + ((u >> 16) & 1u);
    return (ushort)(u >> 16);
}
__device__ __forceinline__ float bf2f(ushort h) {
    unsigned u = ((unsigned)h) << 16;
    return __builtin_bit_cast(float, u);
}

// one 8-ushort cell (row, chunk ch of 16) of a 64x128 tile, fp32 -> bf16
__device__ __forceinline__ short8 cvt_cell(const float* base, int row, int ch) {
    const float4* p = (const float4*)(base + (size_t)row * D_) + ch * 2;
    float4 a = p[0], c = p[1];
    short8 r; ushort* q = (ushort*)&r;
    q[0] = f2bf(a.x); q[1] = f2bf(a.y); q[2] = f2bf(a.z); q[3] = f2bf(a.w);
    q[4] = f2bf(c.x); q[5] = f2bf(c.y); q[6] = f2bf(c.z); q[7] = f2bf(c.w);
    return r;
}

__global__ __launch_bounds__(256, 2)
void entmax_attn(const float* __restrict__ Q, const float* __restrict__ K,
                 const float* __restrict__ V, const int* __restrict__ M,
                 float* __restrict__ O)
{
    __shared__ __align__(16) ushort sc[16][1040];  // scores, then P (bf16)
    __shared__ __align__(16) ushort kv[64][136];   // K/V tile, natural layout
    __shared__ __align__(16) ushort q_s[16][136];  // Q tile

    const int t = threadIdx.x;
    const int w = t >> 6, lane = t & 63, l = lane & 15, quad = lane >> 4;
    const int bh = blockIdx.x >> 6, qt = blockIdx.x & 63, b = bh >> 3;

    const float* kbase = K + (size_t)bh * S_ * D_;
    const float* vbase = V + (size_t)bh * S_ * D_;

    // staging cells: 64x16 = 1024 cells, 4 per thread
    int cr[4], cc[4];
    #pragma unroll
    for (int i = 0; i < 4; ++i) {
        int cell = t + i * 256;
        cr[i] = cell >> 4; cc[i] = cell & 15;
    }

    // ---- stage Q tile (16 rows x 128 f32 -> bf16): 512 float4, 2/thread ----
    {
        const float4* qsrc = (const float4*)(Q + ((size_t)bh * S_ + (size_t)qt * 16) * D_);
        #pragma unroll
        for (int u = 0; u < 2; ++u) {
            int i = t + u * 256, r = i >> 5, c = i & 31;
            float4 v = qsrc[r * 32 + c];
            ushort4 o;
            o.x = f2bf(v.x); o.y = f2bf(v.y); o.z = f2bf(v.z); o.w = f2bf(v.w);
            *(ushort4*)&q_s[r][c * 4] = o;
        }
    }
    // K tile 0 into registers
    short8 sreg[4];
    #pragma unroll
    for (int i = 0; i < 4; ++i) sreg[i] = cvt_cell(kbase, cr[i], cc[i]);

    __syncthreads();                               // q_s visible

    // A-fragments: A[m=lane&15][k=quad*8+j]
    short8 aq[4];
    #pragma unroll
    for (int ks = 0; ks < 4; ++ks)
        aq[ks] = *(const short8*)&q_s[l][ks * 32 + quad * 8];

    #pragma unroll
    for (int i = 0; i < 4; ++i) *(short8*)&kv[cr[i]][cc[i] * 8] = sreg[i];
    __syncthreads();                               // K tile 0 in LDS

    // ---- phase 1: QK^T, dump scaled raw scores to sc -------------------
    #pragma unroll 1
    for (int kt = 0; kt < 16; ++kt) {
        if (kt < 15) {
            const float* nb = kbase + (size_t)(kt + 1) * 64 * D_;
            #pragma unroll
            for (int i = 0; i < 4; ++i) sreg[i] = cvt_cell(nb, cr[i], cc[i]);
        }
        f32x4 acc = {0.f, 0.f, 0.f, 0.f};
        const int n = w * 16 + l;                  // key row in tile (wave=nt)
        #pragma unroll
        for (int ks = 0; ks < 4; ++ks) {
            short8 bk = *(const short8*)&kv[n][ks * 32 + quad * 8];
            acc = __builtin_amdgcn_mfma_f32_16x16x32_bf16(aq[ks], bk, acc, 0, 0, 0);
        }
        // C/D map: col(key)=lane&15 -> key kt*64+w*16+l, row(q)=quad*4+r
        #pragma unroll
        for (int r = 0; r < 4; ++r)
            sc[quad * 4 + r][kt * 64 + w * 16 + l] = f2bf(acc[r] * SCALE_F);
        __syncthreads();                           // kv reads + dumps done
        if (kt < 15) {
            #pragma unroll
            for (int i = 0; i < 4; ++i) *(short8*)&kv[cr[i]][cc[i] * 8] = sreg[i];
            __syncthreads();
        }
    }

    // ---- phase 2: per-row re-gather + mask + max + bisection -----------
    const int row = t >> 4, u = t & 15;            // 16 threads per row
    const int qg = qt * 16 + row;                  // global q row
    float x[64];
    #pragma unroll
    for (int c = 0; c < 8; ++c) {
        short8 v8 = *(const short8*)&sc[row][c * 128 + u * 8];
        #pragma unroll
        for (int e = 0; e < 8; ++e) x[c * 8 + e] = bf2f(((ushort*)&v8)[e]);
    }
    // mask: key = c*128 + u*8 + e
    {
        const int4* mrow = (const int4*)(M + ((size_t)b * S_ + qg) * S_);
        #pragma unroll
        for (int c = 0; c < 8; ++c) {
            #pragma unroll
            for (int h = 0; h < 2; ++h) {
                int4 mm = mrow[c * 32 + u * 2 + h];
                if (mm.x == 0) x[c * 8 + h * 4 + 0] = NEG_INF_F;
                if (mm.y == 0) x[c * 8 + h * 4 + 1] = NEG_INF_F;
                if (mm.z == 0) x[c * 8 + h * 4 + 2] = NEG_INF_F;
                if (mm.w == 0) x[c * 8 + h * 4 + 3] = NEG_INF_F;
            }
        }
    }
    float mx = -3.0e38f;
    #pragma unroll
    for (int j = 0; j < 64; ++j) mx = fmaxf(mx, x[j]);
    #pragma unroll
    for (int off = 1; off < 16; off <<= 1) mx = fmaxf(mx, __shfl_xor(mx, off));
    #pragma unroll
    for (int j = 0; j < 64; ++j) x[j] = (x[j] - mx) * 0.5f;   // x <= 0, max 0

    // bisection: f(tau) = sum max(0,x-tau)^2 = 1, root in [-1,0]
    float lo = -1.f, hi = 0.f;
    #pragma unroll 1
    for (int it = 0; it < NITER; ++it) {
        const float tau = 0.5f * (lo + hi);
        float f = 0.f;
        #pragma unroll
        for (int j = 0; j < 64; ++j) {
            float d = fmaxf(x[j] - tau, 0.f);
            f = fmaf(d, d, f);
        }
        #pragma unroll
        for (int off = 1; off < 16; off <<= 1) f += __shfl_xor(f, off);
        const bool ge = (f >= 1.f);
        lo = ge ? tau : lo;
        hi = ge ? hi : tau;
    }
    const float tau = 0.5f * (lo + hi);

    // y = max(0, x-tau)^2 back into sc (same slots this thread read)
    #pragma unroll
    for (int c = 0; c < 8; ++c) {
        short8 v8;
        #pragma unroll
        for (int e = 0; e < 8; ++e) {
            float d = fmaxf(x[c * 8 + e] - tau, 0.f);
            ((ushort*)&v8)[e] = f2bf(d * d);
        }
        *(short8*)&sc[row][c * 128 + u * 8] = v8;
    }
    // V tile 0 into registers (overlaps)
    #pragma unroll
    for (int i = 0; i < 4; ++i) sreg[i] = cvt_cell(vbase, cr[i], cc[i]);
    __syncthreads();                               // all y visible, kv free
    #pragma unroll
    for (int i = 0; i < 4; ++i) *(short8*)&kv[cr[i]][cc[i] * 8] = sreg[i];
    __syncthreads();                               // V tile 0 in LDS

    // ---- phase 3: O = P @ V; wave w covers d-slices w*16 and 64+w*16 ----
    f32x4 oa[2];
    oa[0] = (f32x4){0.f, 0.f, 0.f, 0.f};
    oa[1] = (f32x4){0.f, 0.f, 0.f, 0.f};
    #pragma unroll 1
    for (int vt = 0; vt < 16; ++vt) {
        if (vt < 15) {
            const float* nb = vbase + (size_t)(vt + 1) * 64 * D_;
            #pragma unroll
            for (int i = 0; i < 4; ++i) sreg[i] = cvt_cell(nb, cr[i], cc[i]);
        }
        #pragma unroll
        for (int ki = 0; ki < 2; ++ki) {
            short8 ap = *(const short8*)&sc[l][vt * 64 + ki * 32 + quad * 8];
            #pragma unroll
            for (int h = 0; h < 2; ++h) {
                const int d = h * 64 + w * 16 + l;
                short8 bv; ushort* bp = (ushort*)&bv;
                #pragma unroll
                for (int j = 0; j < 8; ++j)
                    bp[j] = kv[ki * 32 + quad * 8 + j][d];
                oa[h] = __builtin_amdgcn_mfma_f32_16x16x32_bf16(ap, bv, oa[h], 0, 0, 0);
            }
        }
        __syncthreads();                           // kv reads done
        if (vt < 15) {
            #pragma unroll
            for (int i = 0; i < 4; ++i) *(short8*)&kv[cr[i]][cc[i] * 8] = sreg[i];
            __syncthreads();
        }
    }

    // ---- epilogue: C/D map (col=d=lane&15 within slice, row=q=quad*4+r) --
    float* ob = O + ((size_t)bh * S_ + (size_t)qt * 16) * D_;
    #pragma unroll
    for (int h = 0; h < 2; ++h)
        #pragma unroll
        for (int r = 0; r < 4; ++r)
            ob[(size_t)(quad * 4 + r) * D_ + h * 64 + w * 16 + l] = oa[h][r];
}

extern "C" void kernel_launch(void* const* d_in, const int* in_sizes, int n_in,
                              void* d_out, int out_size, void* d_ws, size_t ws_size,
                              hipStream_t stream) {
    const float* q = (const float*)d_in[0];
    const float* k = (const float*)d_in[1];
    const float* v = (const float*)d_in[2];
    const int*   m = (const int*)d_in[3];
    float*       o = (float*)d_out;
    entmax_attn<<<dim3(2048), dim3(256), 0, stream>>>(q, k, v, m, o);
}

// Round 5
// 214.096 us; speedup vs baseline: 5.6615x; 1.3995x over previous
//
#include <hip/hip_runtime.h>

// entmax-1.5 attention, round 5: round-4 verified structure + conflict-free
// LDS + bf16 pre-converted K / transposed V + 512-thread blocks.
// B=4 H=8 S=1024 D=128. Pre: K->bf16 [bh][key][d]; V->bf16 [bh][d][key].
// Main: 2048 blocks (32 bh x 64 q-tiles of 16 rows), 512 thr (8 waves).
// Phase 1: QK^T (128-key tiles, wave w = keys w*16..w*16+15), raw scaled
//          scores -> sc[16][1028] bf16 via C/D map (col=lane&15,row=quad*4+r).
// Phase 2: 32 threads/row re-gather 32 scores each by direct [row][key]
//          indexing; mask + max + 26-iter bisection (round-4-proven), y back.
// Phase 3: O = P @ V^T-tiles, B-fragments contiguous b128 (V^T layout).

#define S_ 1024
#define D_ 128
#define NEG_INF_F (-1.0e12f)
#define SCALE_F 0.08838834764831845f  // 1/sqrt(128)
#define NITER 26
#define SCP 1028                      // sc row stride (ushorts): 514 words == 2 mod 32

typedef float f32x4 __attribute__((ext_vector_type(4)));
typedef short short8 __attribute__((ext_vector_type(8)));

__device__ __forceinline__ ushort f2bf(float x) {   // RNE f32 -> bf16
    unsigned u = __builtin_bit_cast(unsigned, x);
    u += 0x7FFFu + ((u >> 16) & 1u);
    return (ushort)(u >> 16);
}
__device__ __forceinline__ float bf2f(ushort h) {
    unsigned u = ((unsigned)h) << 16;
    return __builtin_bit_cast(float, u);
}

// ---- pre-kernel 1: K (f32, [bh][key][d]) -> bf16 same layout ------------
__global__ void cvt_k(const float* __restrict__ K, ushort* __restrict__ Kb) {
    int i = blockIdx.x * 256 + threadIdx.x;          // 1,048,576 float4s
    float4 v = ((const float4*)K)[i];
    ushort4 o; o.x = f2bf(v.x); o.y = f2bf(v.y); o.z = f2bf(v.z); o.w = f2bf(v.w);
    ((ushort4*)Kb)[i] = o;
}

// ---- pre-kernel 2: V (f32, [bh][key][d]) -> bf16 transposed [bh][d][key]
__global__ void cvt_vT(const float* __restrict__ V, ushort* __restrict__ Vt) {
    __shared__ ushort tile[128][132];                // [key][d], padded
    const int bh = blockIdx.x >> 3, kt = blockIdx.x & 7;
    const int t = threadIdx.x;
    const float4* src = (const float4*)(V + ((size_t)(bh * S_ + kt * 128)) * D_);
    #pragma unroll
    for (int u = 0; u < 16; ++u) {
        int i = t + u * 256;                         // 0..4095 float4s
        int r = i >> 5, c = i & 31;
        float4 v = src[r * 32 + c];
        ushort4 o; o.x = f2bf(v.x); o.y = f2bf(v.y); o.z = f2bf(v.z); o.w = f2bf(v.w);
        *(ushort4*)&tile[r][c * 4] = o;
    }
    __syncthreads();
    const int d = t >> 1, h = t & 1;
    ushort* dst = Vt + ((size_t)(bh * D_ + d)) * S_ + kt * 128 + h * 64;
    #pragma unroll
    for (int jj = 0; jj < 8; ++jj) {
        short8 val;
        #pragma unroll
        for (int e = 0; e < 8; ++e)
            ((ushort*)&val)[e] = tile[h * 64 + jj * 8 + e][d];
        *(short8*)(dst + jj * 8) = val;
    }
}

// ---- main kernel --------------------------------------------------------
__global__ __launch_bounds__(512, 4)
void entmax_attn(const float* __restrict__ Q, const ushort* __restrict__ Kb,
                 const ushort* __restrict__ Vt, const int* __restrict__ M,
                 float* __restrict__ O)
{
    __shared__ __align__(16) ushort sc[16][SCP];   // scores, then P (bf16)
    __shared__ __align__(16) ushort kv[128][136];  // K tile [key][d] / V^T tile [d][key]
    __shared__ __align__(16) ushort q_s[16][136];  // Q tile bf16

    const int t = threadIdx.x;
    const int w = t >> 6, lane = t & 63, l = lane & 15, quad = lane >> 4;
    const int bh = blockIdx.x >> 6, qt = blockIdx.x & 63, b = bh >> 3;

    const ushort* kb_bh = Kb + (size_t)bh * S_ * D_;
    const ushort* vt_bh = Vt + (size_t)bh * D_ * S_;

    // staging cells: 128 rows x 16 chunks = 2048 ushort8 cells, 4 per thread
    int cr[4], cc[4];
    #pragma unroll
    for (int i = 0; i < 4; ++i) {
        int cell = t + i * 512;
        cr[i] = cell >> 4; cc[i] = cell & 15;
    }

    // ---- stage Q tile (16x128 fp32 -> bf16): 512 float4, 1/thread -------
    {
        const float4* qsrc = (const float4*)(Q + ((size_t)bh * S_ + (size_t)qt * 16) * D_);
        int r = t >> 5, c = t & 31;
        float4 v = qsrc[r * 32 + c];
        ushort4 o;
        o.x = f2bf(v.x); o.y = f2bf(v.y); o.z = f2bf(v.z); o.w = f2bf(v.w);
        *(ushort4*)&q_s[r][c * 4] = o;
    }
    // K tile 0 into registers (bf16 ushort8, coalesced)
    short8 sreg[4];
    #pragma unroll
    for (int i = 0; i < 4; ++i)
        sreg[i] = *(const short8*)(kb_bh + (size_t)cr[i] * D_ + cc[i] * 8);

    __syncthreads();                               // q_s visible

    // A-fragments (Q): A[m=lane&15][k=quad*8+j]
    short8 aq[4];
    #pragma unroll
    for (int ks = 0; ks < 4; ++ks)
        aq[ks] = *(const short8*)&q_s[l][ks * 32 + quad * 8];

    #pragma unroll
    for (int i = 0; i < 4; ++i) *(short8*)&kv[cr[i]][cc[i] * 8] = sreg[i];
    __syncthreads();                               // K tile 0 in LDS

    // ---- phase 1: QK^T, 8 tiles of 128 keys; dump scaled scores --------
    #pragma unroll 1
    for (int kt = 0; kt < 8; ++kt) {
        if (kt < 7) {
            const ushort* nb = kb_bh + (size_t)(kt + 1) * 128 * D_;
            #pragma unroll
            for (int i = 0; i < 4; ++i)
                sreg[i] = *(const short8*)(nb + (size_t)cr[i] * D_ + cc[i] * 8);
        }
        f32x4 acc = {0.f, 0.f, 0.f, 0.f};
        const int n = w * 16 + l;                  // this wave's key row
        #pragma unroll
        for (int ks = 0; ks < 4; ++ks) {
            short8 bk = *(const short8*)&kv[n][ks * 32 + quad * 8];
            acc = __builtin_amdgcn_mfma_f32_16x16x32_bf16(aq[ks], bk, acc, 0, 0, 0);
        }
        // C/D map: col(key within wave group)=l, row(q)=quad*4+r
        #pragma unroll
        for (int r = 0; r < 4; ++r)
            sc[quad * 4 + r][kt * 128 + w * 16 + l] = f2bf(acc[r] * SCALE_F);
        __syncthreads();                           // kv reads + dumps done
        if (kt < 7) {
            #pragma unroll
            for (int i = 0; i < 4; ++i) *(short8*)&kv[cr[i]][cc[i] * 8] = sreg[i];
            __syncthreads();
        }
    }

    // V^T tile 0 into registers (latency hides under the solver)
    #pragma unroll
    for (int i = 0; i < 4; ++i)
        sreg[i] = *(const short8*)(vt_bh + (size_t)cr[i] * S_ + cc[i] * 8);

    // ---- phase 2: per-row re-gather + mask + max + bisection -----------
    const int row = t >> 5, u = t & 31;            // 32 threads per row
    const int qg = qt * 16 + row;
    float x[32];
    #pragma unroll
    for (int c = 0; c < 4; ++c) {
        short8 v8 = *(const short8*)&sc[row][c * 256 + u * 8];
        #pragma unroll
        for (int e = 0; e < 8; ++e) x[c * 8 + e] = bf2f(((ushort*)&v8)[e]);
    }
    {   // mask: key = c*256 + u*8 + h*4 + e
        const int4* mrow = (const int4*)(M + ((size_t)b * S_ + qg) * S_);
        #pragma unroll
        for (int c = 0; c < 4; ++c) {
            #pragma unroll
            for (int h = 0; h < 2; ++h) {
                int4 mm = mrow[c * 64 + u * 2 + h];
                if (mm.x == 0) x[c * 8 + h * 4 + 0] = NEG_INF_F;
                if (mm.y == 0) x[c * 8 + h * 4 + 1] = NEG_INF_F;
                if (mm.z == 0) x[c * 8 + h * 4 + 2] = NEG_INF_F;
                if (mm.w == 0) x[c * 8 + h * 4 + 3] = NEG_INF_F;
            }
        }
    }
    float mx = -3.0e38f;
    #pragma unroll
    for (int j = 0; j < 32; ++j) mx = fmaxf(mx, x[j]);
    #pragma unroll
    for (int off = 1; off < 32; off <<= 1) mx = fmaxf(mx, __shfl_xor(mx, off));
    #pragma unroll
    for (int j = 0; j < 32; ++j) x[j] = (x[j] - mx) * 0.5f;   // x <= 0

    float lo = -1.f, hi = 0.f;                     // f(-1)>=1, monotone dec
    #pragma unroll 1
    for (int it = 0; it < NITER; ++it) {
        const float tau = 0.5f * (lo + hi);
        float f = 0.f;
        #pragma unroll
        for (int j = 0; j < 32; ++j) {
            float d = fmaxf(x[j] - tau, 0.f);
            f = fmaf(d, d, f);
        }
        #pragma unroll
        for (int off = 1; off < 32; off <<= 1) f += __shfl_xor(f, off);
        const bool ge = (f >= 1.f);
        lo = ge ? tau : lo;
        hi = ge ? hi : tau;
    }
    const float tau = 0.5f * (lo + hi);

    #pragma unroll
    for (int c = 0; c < 4; ++c) {                  // y back into sc
        short8 v8;
        #pragma unroll
        for (int e = 0; e < 8; ++e) {
            float d = fmaxf(x[c * 8 + e] - tau, 0.f);
            ((ushort*)&v8)[e] = f2bf(d * d);
        }
        *(short8*)&sc[row][c * 256 + u * 8] = v8;
    }
    #pragma unroll
    for (int i = 0; i < 4; ++i) *(short8*)&kv[cr[i]][cc[i] * 8] = sreg[i];  // V^T tile 0
    __syncthreads();                               // y + V tile visible

    // ---- phase 3: O = P @ V; wave w owns d-slice w*16..w*16+15 ---------
    f32x4 oa = {0.f, 0.f, 0.f, 0.f};
    #pragma unroll 1
    for (int vt = 0; vt < 8; ++vt) {
        if (vt < 7) {
            const ushort* nb = vt_bh + (size_t)(vt + 1) * 128;
            #pragma unroll
            for (int i = 0; i < 4; ++i)
                sreg[i] = *(const short8*)(nb + (size_t)cr[i] * S_ + cc[i] * 8);
        }
        const int d = w * 16 + l;                  // V^T LDS row = d
        #pragma unroll
        for (int ki = 0; ki < 4; ++ki) {
            short8 ap = *(const short8*)&sc[l][vt * 128 + ki * 32 + quad * 8];
            short8 bv = *(const short8*)&kv[d][ki * 32 + quad * 8];
            oa = __builtin_amdgcn_mfma_f32_16x16x32_bf16(ap, bv, oa, 0, 0, 0);
        }
        __syncthreads();                           // kv reads done
        if (vt < 7) {
            #pragma unroll
            for (int i = 0; i < 4; ++i) *(short8*)&kv[cr[i]][cc[i] * 8] = sreg[i];
            __syncthreads();
        }
    }

    // ---- epilogue: C/D map (col=d-within-slice=l, row=q=quad*4+r) ------
    float* ob = O + ((size_t)bh * S_ + (size_t)qt * 16) * D_;
    #pragma unroll
    for (int r = 0; r < 4; ++r)
        ob[(size_t)(quad * 4 + r) * D_ + w * 16 + l] = oa[r];
}

extern "C" void kernel_launch(void* const* d_in, const int* in_sizes, int n_in,
                              void* d_out, int out_size, void* d_ws, size_t ws_size,
                              hipStream_t stream) {
    const float* q = (const float*)d_in[0];
    const float* k = (const float*)d_in[1];
    const float* v = (const float*)d_in[2];
    const int*   m = (const int*)d_in[3];
    float*       o = (float*)d_out;

    ushort* Kb = (ushort*)d_ws;                      // 8,388,608 B
    ushort* Vt = (ushort*)((char*)d_ws + 8388608);   // 8,388,608 B

    cvt_k <<<4096, 256, 0, stream>>>(k, Kb);
    cvt_vT<<<256, 256, 0, stream>>>(v, Vt);
    entmax_attn<<<2048, 512, 0, stream>>>(q, Kb, Vt, m, o);
}

// Round 6
// 204.423 us; speedup vs baseline: 5.9294x; 1.0473x over previous
//
#include <hip/hip_runtime.h>

// entmax-1.5 attention, round 6: round-5 verified structure + candidate-
// compacted tau solver + fast fused pre-kernel.
// B=4 H=8 S=1024 D=128. Pre: K->bf16 [bh][key][d]; V->bf16 [bh][d][key].
// Main: 2048 blocks (32 bh x 64 q-tiles of 16 rows), 512 thr (8 waves).
// Phase 1: QK^T (128-key tiles), raw scaled scores -> sc bf16 via C/D map.
// Phase 2: 32 thr/row regather+mask+max+normalize; ballot-compact the exact
//          candidate set {x > -1} (only these can enter the support, since
//          tau* >= -1) into LDS (overlaid on kv); 14-iter bisection over
//          candidates only. Fallback to full register solve if cnt > 512
//          (also covers all-masked rows). y written back dense to sc.
// Phase 3: O = P @ V^T-tiles, contiguous b128 fragments (verified r5).

#define S_ 1024
#define D_ 128
#define NEG_INF_F (-1.0e12f)
#define SCALE_F 0.08838834764831845f  // 1/sqrt(128)
#define NITER 14                      // dTau=6e-5 -> out err ~1e-3 << 0.0766
#define SCP 1028                      // sc row stride (ushorts)
#define CCAP 512                      // candidate cap per row
#define CSTR 516                      // candidate row stride (floats)

typedef float f32x4 __attribute__((ext_vector_type(4)));
typedef short short8 __attribute__((ext_vector_type(8)));

__device__ __forceinline__ ushort f2bf(float x) {   // RNE f32 -> bf16
    unsigned u = __builtin_bit_cast(unsigned, x);
    u += 0x7FFFu + ((u >> 16) & 1u);
    return (ushort)(u >> 16);
}
__device__ __forceinline__ float bf2f(ushort h) {
    unsigned u = ((unsigned)h) << 16;
    return __builtin_bit_cast(float, u);
}

// ---- fused pre-kernel: blocks 0..4095 K->bf16; 4096..5119 V->bf16-T ----
__global__ __launch_bounds__(256)
void pre_cvt(const float* __restrict__ K, const float* __restrict__ V,
             ushort* __restrict__ Kb, ushort* __restrict__ Vt)
{
    __shared__ ushort tile[64][72];
    const int t = threadIdx.x;
    if (blockIdx.x < 4096) {                       // K convert (coalesced)
        int i = blockIdx.x * 256 + t;              // 1,048,576 float4s
        float4 v = ((const float4*)K)[i];
        ushort4 o;
        o.x = f2bf(v.x); o.y = f2bf(v.y); o.z = f2bf(v.z); o.w = f2bf(v.w);
        ((ushort4*)Kb)[i] = o;
        return;
    }
    // V transpose: 64x64 tile per block. 1024 blocks = 32 bh x 16 kt x 2 dh
    const int vb = blockIdx.x - 4096;
    const int bh = vb >> 5, r5 = vb & 31, kt = r5 >> 1, dh = r5 & 1;
    const float* src = V + ((size_t)(bh * S_ + kt * 64)) * D_ + dh * 64;
    #pragma unroll
    for (int i = 0; i < 4; ++i) {                  // 1024 float4 loads
        int idx = t + i * 256, r = idx >> 4, c = idx & 15;
        float4 vv = *(const float4*)(src + (size_t)r * D_ + c * 4);
        ushort4 o;
        o.x = f2bf(vv.x); o.y = f2bf(vv.y); o.z = f2bf(vv.z); o.w = f2bf(vv.w);
        *(ushort4*)&tile[r][c * 4] = o;
    }
    __syncthreads();
    ushort* dst = Vt + ((size_t)(bh * D_ + dh * 64)) * S_ + kt * 64;
    #pragma unroll
    for (int i = 0; i < 2; ++i) {                  // 512 short8 stores
        int idx = t + i * 256, d = idx >> 3, jj = idx & 7;
        short8 val; ushort* vp = (ushort*)&val;
        #pragma unroll
        for (int e = 0; e < 8; ++e) vp[e] = tile[jj * 8 + e][d];
        *(short8*)(dst + (size_t)d * S_ + jj * 8) = val;
    }
}

// ---- main kernel --------------------------------------------------------
__global__ __launch_bounds__(512, 4)
void entmax_attn(const float* __restrict__ Q, const ushort* __restrict__ Kb,
                 const ushort* __restrict__ Vt, const int* __restrict__ M,
                 float* __restrict__ O)
{
    __shared__ __align__(16) ushort sc[16][SCP];   // scores, then P (bf16)
    __shared__ __align__(16) ushort kv[128][136];  // K/V^T tile; cand overlay
    __shared__ __align__(16) ushort q_s[16][136];  // Q tile bf16

    const int t = threadIdx.x;
    const int w = t >> 6, lane = t & 63, l = lane & 15, quad = lane >> 4;
    const int bh = blockIdx.x >> 6, qt = blockIdx.x & 63, b = bh >> 3;

    const ushort* kb_bh = Kb + (size_t)bh * S_ * D_;
    const ushort* vt_bh = Vt + (size_t)bh * D_ * S_;

    // staging cells: 128 rows x 16 chunks = 2048 ushort8 cells, 4/thread
    int cr[4], cc[4];
    #pragma unroll
    for (int i = 0; i < 4; ++i) {
        int cell = t + i * 512;
        cr[i] = cell >> 4; cc[i] = cell & 15;
    }

    // ---- stage Q tile (16x128 fp32 -> bf16) ----------------------------
    {
        const float4* qsrc = (const float4*)(Q + ((size_t)bh * S_ + (size_t)qt * 16) * D_);
        int r = t >> 5, c = t & 31;
        float4 v = qsrc[r * 32 + c];
        ushort4 o;
        o.x = f2bf(v.x); o.y = f2bf(v.y); o.z = f2bf(v.z); o.w = f2bf(v.w);
        *(ushort4*)&q_s[r][c * 4] = o;
    }
    short8 sreg[4];
    #pragma unroll
    for (int i = 0; i < 4; ++i)
        sreg[i] = *(const short8*)(kb_bh + (size_t)cr[i] * D_ + cc[i] * 8);

    __syncthreads();                               // q_s visible

    short8 aq[4];                                  // A[m=lane&15][k=quad*8+j]
    #pragma unroll
    for (int ks = 0; ks < 4; ++ks)
        aq[ks] = *(const short8*)&q_s[l][ks * 32 + quad * 8];

    #pragma unroll
    for (int i = 0; i < 4; ++i) *(short8*)&kv[cr[i]][cc[i] * 8] = sreg[i];
    __syncthreads();                               // K tile 0 in LDS

    // ---- phase 1: QK^T, 8 tiles of 128 keys; dump scaled scores --------
    #pragma unroll 1
    for (int kt = 0; kt < 8; ++kt) {
        if (kt < 7) {
            const ushort* nb = kb_bh + (size_t)(kt + 1) * 128 * D_;
            #pragma unroll
            for (int i = 0; i < 4; ++i)
                sreg[i] = *(const short8*)(nb + (size_t)cr[i] * D_ + cc[i] * 8);
        }
        f32x4 acc = {0.f, 0.f, 0.f, 0.f};
        const int n = w * 16 + l;
        #pragma unroll
        for (int ks = 0; ks < 4; ++ks) {
            short8 bk = *(const short8*)&kv[n][ks * 32 + quad * 8];
            acc = __builtin_amdgcn_mfma_f32_16x16x32_bf16(aq[ks], bk, acc, 0, 0, 0);
        }
        #pragma unroll
        for (int r = 0; r < 4; ++r)
            sc[quad * 4 + r][kt * 128 + w * 16 + l] = f2bf(acc[r] * SCALE_F);
        __syncthreads();
        if (kt < 7) {
            #pragma unroll
            for (int i = 0; i < 4; ++i) *(short8*)&kv[cr[i]][cc[i] * 8] = sreg[i];
            __syncthreads();
        }
    }

    // V^T tile 0 into registers now (global; latency hides under solver)
    #pragma unroll
    for (int i = 0; i < 4; ++i)
        sreg[i] = *(const short8*)(vt_bh + (size_t)cr[i] * S_ + cc[i] * 8);

    // ---- phase 2: regather + mask + max + normalize --------------------
    const int row = t >> 5, u = t & 31;            // 32 threads per row
    const int qg = qt * 16 + row;
    float x[32];
    #pragma unroll
    for (int c = 0; c < 4; ++c) {
        short8 v8 = *(const short8*)&sc[row][c * 256 + u * 8];
        #pragma unroll
        for (int e = 0; e < 8; ++e) x[c * 8 + e] = bf2f(((ushort*)&v8)[e]);
    }
    {   // mask: key = c*256 + u*8 + h*4 + e
        const int4* mrow = (const int4*)(M + ((size_t)b * S_ + qg) * S_);
        #pragma unroll
        for (int c = 0; c < 4; ++c) {
            #pragma unroll
            for (int h = 0; h < 2; ++h) {
                int4 mm = mrow[c * 64 + u * 2 + h];
                if (mm.x == 0) x[c * 8 + h * 4 + 0] = NEG_INF_F;
                if (mm.y == 0) x[c * 8 + h * 4 + 1] = NEG_INF_F;
                if (mm.z == 0) x[c * 8 + h * 4 + 2] = NEG_INF_F;
                if (mm.w == 0) x[c * 8 + h * 4 + 3] = NEG_INF_F;
            }
        }
    }
    float mx = -3.0e38f;
    #pragma unroll
    for (int j = 0; j < 32; ++j) mx = fmaxf(mx, x[j]);
    #pragma unroll
    for (int off = 1; off < 32; off <<= 1) mx = fmaxf(mx, __shfl_xor(mx, off));
    #pragma unroll
    for (int j = 0; j < 32; ++j) x[j] = (x[j] - mx) * 0.5f;   // x <= 0

    // ---- candidate compaction: exact set {x > -1} (tau* >= -1) ---------
    // cand overlays kv (dead until V store). 16 rows x CSTR floats = 33 KB.
    float* cand = (float*)&kv[0][0];
    const unsigned long long halfmask =
        (lane >= 32) ? 0xFFFFFFFF00000000ull : 0x00000000FFFFFFFFull;
    int cnt = 0;
    #pragma unroll
    for (int j = 0; j < 32; ++j) {
        const bool p = (x[j] > -1.0f);
        unsigned long long bal = __ballot(p) & halfmask;
        if (p) {
            int pos = cnt + (int)__builtin_amdgcn_mbcnt_hi(
                (unsigned)(bal >> 32),
                __builtin_amdgcn_mbcnt_lo((unsigned)bal, 0));
            if (pos < CCAP) cand[row * CSTR + pos] = x[j];
        }
        cnt += __popcll(bal);
    }

    // ---- tau bisection on f(tau)=sum max(0,x-tau)^2=1, root in [-1,0] --
    float tau;
    if (cnt <= CCAP) {                             // compact path (normal)
        const float* crow = cand + row * CSTR;
        float lo = -1.f, hi = 0.f;
        #pragma unroll 1
        for (int it = 0; it < NITER; ++it) {
            const float tm = 0.5f * (lo + hi);
            float f = 0.f;
            for (int j = u; j < cnt; j += 32) {
                float d = fmaxf(crow[j] - tm, 0.f);
                f = fmaf(d, d, f);
            }
            #pragma unroll
            for (int off = 1; off < 32; off <<= 1) f += __shfl_xor(f, off);
            const bool ge = (f >= 1.f);
            lo = ge ? tm : lo;
            hi = ge ? hi : tm;
        }
        tau = 0.5f * (lo + hi);
    } else {                                       // fallback: full solve
        float lo = -1.f, hi = 0.f;
        #pragma unroll 1
        for (int it = 0; it < NITER; ++it) {
            const float tm = 0.5f * (lo + hi);
            float f = 0.f;
            #pragma unroll
            for (int j = 0; j < 32; ++j) {
                float d = fmaxf(x[j] - tm, 0.f);
                f = fmaf(d, d, f);
            }
            #pragma unroll
            for (int off = 1; off < 32; off <<= 1) f += __shfl_xor(f, off);
            const bool ge = (f >= 1.f);
            lo = ge ? tm : lo;
            hi = ge ? hi : tm;
        }
        tau = 0.5f * (lo + hi);
    }

    // ---- y = max(0,x-tau)^2 back into sc (dense) -----------------------
    #pragma unroll
    for (int c = 0; c < 4; ++c) {
        short8 v8;
        #pragma unroll
        for (int e = 0; e < 8; ++e) {
            float d = fmaxf(x[c * 8 + e] - tau, 0.f);
            ((ushort*)&v8)[e] = f2bf(d * d);
        }
        *(short8*)&sc[row][c * 256 + u * 8] = v8;
    }
    __syncthreads();                               // cand reads + y writes done
    #pragma unroll
    for (int i = 0; i < 4; ++i) *(short8*)&kv[cr[i]][cc[i] * 8] = sreg[i];
    __syncthreads();                               // V tile 0 + y visible

    // ---- phase 3: O = P @ V; wave w owns d-slice w*16..w*16+15 ---------
    f32x4 oa = {0.f, 0.f, 0.f, 0.f};
    #pragma unroll 1
    for (int vt = 0; vt < 8; ++vt) {
        if (vt < 7) {
            const ushort* nb = vt_bh + (size_t)(vt + 1) * 128;
            #pragma unroll
            for (int i = 0; i < 4; ++i)
                sreg[i] = *(const short8*)(nb + (size_t)cr[i] * S_ + cc[i] * 8);
        }
        const int d = w * 16 + l;
        #pragma unroll
        for (int ki = 0; ki < 4; ++ki) {
            short8 ap = *(const short8*)&sc[l][vt * 128 + ki * 32 + quad * 8];
            short8 bv = *(const short8*)&kv[d][ki * 32 + quad * 8];
            oa = __builtin_amdgcn_mfma_f32_16x16x32_bf16(ap, bv, oa, 0, 0, 0);
        }
        __syncthreads();
        if (vt < 7) {
            #pragma unroll
            for (int i = 0; i < 4; ++i) *(short8*)&kv[cr[i]][cc[i] * 8] = sreg[i];
            __syncthreads();
        }
    }

    // ---- epilogue: C/D map (col=d-within-slice=l, row=q=quad*4+r) ------
    float* ob = O + ((size_t)bh * S_ + (size_t)qt * 16) * D_;
    #pragma unroll
    for (int r = 0; r < 4; ++r)
        ob[(size_t)(quad * 4 + r) * D_ + w * 16 + l] = oa[r];
}

extern "C" void kernel_launch(void* const* d_in, const int* in_sizes, int n_in,
                              void* d_out, int out_size, void* d_ws, size_t ws_size,
                              hipStream_t stream) {
    const float* q = (const float*)d_in[0];
    const float* k = (const float*)d_in[1];
    const float* v = (const float*)d_in[2];
    const int*   m = (const int*)d_in[3];
    float*       o = (float*)d_out;

    ushort* Kb = (ushort*)d_ws;                      // 8,388,608 B
    ushort* Vt = (ushort*)((char*)d_ws + 8388608);   // 8,388,608 B

    pre_cvt<<<5120, 256, 0, stream>>>(k, v, Kb, Vt);
    entmax_attn<<<2048, 512, 0, stream>>>(q, Kb, Vt, m, o);
}